// Round 11
// baseline (353.810 us; speedup 1.0000x reference)
//
#include <hip/hip_runtime.h>
#include <math.h>

#define NN    16384     // nodes
#define DIN   1024
#define HCdim 512       // H*C
#define NHEAD 4
#define NE_   262144    // edges (without self loops)
#define EP_   (NE_ + NN) // with self loops

using short8  = __attribute__((ext_vector_type(8))) short;
using floatx4 = __attribute__((ext_vector_type(4))) float;

typedef __attribute__((address_space(3))) unsigned int lds_uint;
typedef const __attribute__((address_space(1))) unsigned int glb_uint;
#define ASYNC_LD16(g, l) __builtin_amdgcn_global_load_lds((glb_uint*)(g), (lds_uint*)(l), 16, 0, 0)

__device__ __forceinline__ float eluf(float x){ return x > 0.f ? x : expm1f(x); }
__device__ __forceinline__ float lrelu(float x){ return x > 0.f ? x : 0.2f * x; }
__device__ __forceinline__ float bf2f(unsigned short u){
    union { unsigned int i; float f; } c; c.i = ((unsigned int)u) << 16; return c.f;
}
__device__ __forceinline__ unsigned short f2b(float f){
    union { float f; unsigned int u; } c; c.f = f;
    unsigned int u = c.u;
    return (unsigned short)((u + 0x7FFFu + ((u >> 16) & 1u)) >> 16);   // RNE
}

// ---------------- CSR build ----------------
__global__ void k_zero_i(int* __restrict__ p, int n){
    int i = blockIdx.x * 256 + threadIdx.x;
    if (i < n) p[i] = 0;
}

__global__ void k_degree(const int* __restrict__ ei, int* __restrict__ deg){
    int i = blockIdx.x * 256 + threadIdx.x;
    if (i >= EP_) return;
    int d = (i < NE_) ? ei[NE_ + i] : (i - NE_);
    atomicAdd(&deg[d], 1);
}

__global__ __launch_bounds__(1024) void k_scan(const int* __restrict__ deg, int* __restrict__ offs){
    __shared__ int s[1024];
    int tid  = threadIdx.x;
    int base = tid * 16;
    int local[16];
    int sum = 0;
    #pragma unroll
    for (int i = 0; i < 16; i++){ local[i] = deg[base + i]; sum += local[i]; }
    s[tid] = sum;
    __syncthreads();
    for (int off = 1; off < 1024; off <<= 1){
        int v = (tid >= off) ? s[tid - off] : 0;
        __syncthreads();
        s[tid] += v;
        __syncthreads();
    }
    int run = (tid == 0) ? 0 : s[tid - 1];
    #pragma unroll
    for (int i = 0; i < 16; i++){ offs[base + i] = run; run += local[i]; }
    if (tid == 1023) offs[NN] = run;
}

__global__ void k_scatter(const int* __restrict__ ei, const int* __restrict__ offs,
                          int* __restrict__ cursor, int* __restrict__ csr){
    int i = blockIdx.x * 256 + threadIdx.x;
    if (i >= EP_) return;
    int srcv, dstv;
    if (i < NE_){ srcv = ei[i]; dstv = ei[NE_ + i]; }
    else        { srcv = dstv = i - NE_; }
    int pos = offs[dstv] + atomicAdd(&cursor[dstv], 1);
    csr[pos] = srcv;
}

// ---------------- merged casts: x -> bf16 ; W1,W2 -> bf16 transposed ----------------
__global__ __launch_bounds__(256) void k_casts(const float* __restrict__ x, ushort* __restrict__ xb,
    const float* __restrict__ W1, ushort* __restrict__ W1T,
    const float* __restrict__ W2, ushort* __restrict__ W2T){
    int bid = blockIdx.x, tid = threadIdx.x;
    if (bid < 16384){
        int i = bid * 256 + tid;
        float4 v = *(const float4*)(x + (size_t)i * 4);
        ushort4 o = { f2b(v.x), f2b(v.y), f2b(v.z), f2b(v.w) };
        *(ushort4*)(xb + (size_t)i * 4) = o;
    } else if (bid < 16384 + 512){
        int t = (bid - 16384) * 256 + tid;          // W1: 1024x512 -> T
        int n = t >> 8, kb = (t & 255) * 4;
        ushort4 o = { f2b(W1[(size_t)(kb+0)*HCdim + n]), f2b(W1[(size_t)(kb+1)*HCdim + n]),
                      f2b(W1[(size_t)(kb+2)*HCdim + n]), f2b(W1[(size_t)(kb+3)*HCdim + n]) };
        *(ushort4*)(W1T + (size_t)n * DIN + kb) = o;
    } else {
        int t = (bid - 16896) * 256 + tid;          // W2: 512x512 -> T
        int n = t >> 7, kb = (t & 127) * 4;
        ushort4 o = { f2b(W2[(size_t)(kb+0)*HCdim + n]), f2b(W2[(size_t)(kb+1)*HCdim + n]),
                      f2b(W2[(size_t)(kb+2)*HCdim + n]), f2b(W2[(size_t)(kb+3)*HCdim + n]) };
        *(ushort4*)(W2T + (size_t)n * HCdim + kb) = o;
    }
}

// ---------------- bf16 MFMA GEMM (64x128 tile) -> adaptive int8 C + fused attention epilogue ----------------
// C[M,512] = A[M,K] @ BT[512,K]^T, stored int8 with scl[node][head] = absmax/127.
// 64-node x 128-channel block => grid (4, M/64) = 1024 blocks = 4 blocks/CU (occupancy fix).
// Operand-swapped MFMA: acc=mfma(bf,af) => regs = channels, lanes = nodes.
__global__ __launch_bounds__(256) void gemm_bf16(const ushort* __restrict__ A,
                                                 const ushort* __restrict__ BT,
                                                 signed char* __restrict__ C,
                                                 const float* __restrict__ att_s,
                                                 const float* __restrict__ att_d,
                                                 float* __restrict__ as_, float* __restrict__ ad_,
                                                 float* __restrict__ sclb,
                                                 int M, int Nn, int K){
    __shared__ ushort As[64 * 32];
    __shared__ ushort Bs[128 * 32];
    __shared__ float prS[2][64];
    __shared__ float prD[2][64];
    __shared__ float amx[2][64];
    int tid = threadIdx.x;
    int m0 = blockIdx.y * 64, n0 = blockIdx.x * 128;
    int cx = blockIdx.x;                 // head
    int lane = tid & 63, w = tid >> 6;
    int wm = (w >> 1) * 32, wn = (w & 1) * 64;   // wm: node offset (0/32), wn: channel offset (0/64)
    int la = lane & 15, qd = lane >> 4;

    int srow = tid >> 2, schunk = (tid & 3) * 8;   // srow 0..63
    const ushort* Ag = A  + (size_t)(m0 + srow) * K + schunk;
    const ushort* Bg = BT + (size_t)(n0 + srow) * K + schunk;
    ushort* Asw = &As[srow * 32 + schunk];
    ushort* Bsw = &Bs[srow * 32 + schunk];

    floatx4 acc[4][2] = {};   // acc[i=channel-block<4][j=node-block<2]
    for (int k0 = 0; k0 < K; k0 += 32){
        __syncthreads();
        ASYNC_LD16(Ag + k0,                  Asw);
        ASYNC_LD16(Bg + k0,                  Bsw);
        ASYNC_LD16(Bg + (size_t)64 * K + k0, Bsw + 64 * 32);
        __syncthreads();
        short8 af[2], bf[4];
        #pragma unroll
        for (int i = 0; i < 2; i++)
            af[i] = *(const short8*)&As[(wm + i*16 + la) * 32 + qd * 8];  // nodes
        #pragma unroll
        for (int i = 0; i < 4; i++)
            bf[i] = *(const short8*)&Bs[(wn + i*16 + la) * 32 + qd * 8];  // channels
        #pragma unroll
        for (int i = 0; i < 4; i++)
            #pragma unroll
            for (int j = 0; j < 2; j++)
                acc[i][j] = __builtin_amdgcn_mfma_f32_16x16x32_bf16(bf[i], af[j], acc[i][j], 0, 0, 0);
    }
    // attention partials: lane's channels = wn + i*16 + qd*4 + r ; node = wm + j*16 + la
    float4 s4[4], d4[4];
    #pragma unroll
    for (int i = 0; i < 4; i++){
        s4[i] = *(const float4*)(att_s + cx * 128 + wn + i * 16 + qd * 4);
        d4[i] = *(const float4*)(att_d + cx * 128 + wn + i * 16 + qd * 4);
    }
    int half = wn >> 6;
    #pragma unroll
    for (int j = 0; j < 2; j++){
        float ps = 0.f, pd = 0.f;
        #pragma unroll
        for (int i = 0; i < 4; i++){
            ps = fmaf(acc[i][j][0], s4[i].x, ps); pd = fmaf(acc[i][j][0], d4[i].x, pd);
            ps = fmaf(acc[i][j][1], s4[i].y, ps); pd = fmaf(acc[i][j][1], d4[i].y, pd);
            ps = fmaf(acc[i][j][2], s4[i].z, ps); pd = fmaf(acc[i][j][2], d4[i].z, pd);
            ps = fmaf(acc[i][j][3], s4[i].w, ps); pd = fmaf(acc[i][j][3], d4[i].w, pd);
        }
        ps += __shfl_xor(ps, 16); ps += __shfl_xor(ps, 32);
        pd += __shfl_xor(pd, 16); pd += __shfl_xor(pd, 32);
        // per-node absmax over this wave's 64 channels
        float am = 0.f;
        #pragma unroll
        for (int i = 0; i < 4; i++){
            am = fmaxf(am, fabsf(acc[i][j][0])); am = fmaxf(am, fabsf(acc[i][j][1]));
            am = fmaxf(am, fabsf(acc[i][j][2])); am = fmaxf(am, fabsf(acc[i][j][3]));
        }
        am = fmaxf(am, __shfl_xor(am, 16)); am = fmaxf(am, __shfl_xor(am, 32));
        if (lane < 16){            // qd == 0 holds full reductions
            prS[half][wm + j * 16 + la] = ps;
            prD[half][wm + j * 16 + la] = pd;
            amx[half][wm + j * 16 + la] = am;
        }
    }
    __syncthreads();
    // quantized C store: node = m0+wm+j*16+la, channels n0+wn+i*16+qd*4 .. +3
    #pragma unroll
    for (int j = 0; j < 2; j++){
        int nl = wm + j * 16 + la;
        float amax = fmaxf(fmaxf(amx[0][nl], amx[1][nl]), 1e-20f);
        float inv = 127.0f / amax;
        #pragma unroll
        for (int i = 0; i < 4; i++){
            int q0 = (int)rintf(acc[i][j][0] * inv);
            int q1 = (int)rintf(acc[i][j][1] * inv);
            int q2 = (int)rintf(acc[i][j][2] * inv);
            int q3 = (int)rintf(acc[i][j][3] * inv);
            unsigned pk = (q0 & 0xff) | ((q1 & 0xff) << 8) | ((q2 & 0xff) << 16) | ((q3 & 0xff) << 24);
            *(unsigned*)(C + (size_t)(m0 + nl) * HCdim + n0 + wn + i * 16 + qd * 4) = pk;
        }
    }
    if (tid < 64){
        as_[(size_t)(m0 + tid) * 4 + cx]  = prS[0][tid] + prS[1][tid];
        ad_[(size_t)(m0 + tid) * 4 + cx]  = prD[0][tid] + prD[1][tid];
        sclb[(size_t)(m0 + tid) * 4 + cx] = fmaxf(fmaxf(amx[0][tid], amx[1][tid]), 1e-20f) * (1.f / 127.f);
    }
}

// ---------------- edge weights: wbuf[j][h] = {bf16 w, bf16 w*scl[src][h]} packed in uint ----------------
__global__ __launch_bounds__(256) void k_edgew(const int* __restrict__ offs, const int* __restrict__ csr,
    const float* __restrict__ as_, const float* __restrict__ ad_,
    const float* __restrict__ sclb, unsigned* __restrict__ wbuf){
    int wv = threadIdx.x >> 6, lane = threadIdx.x & 63;
    int n = blockIdx.x * 4 + wv;
    int start = offs[n], end = offs[n + 1];
    float4 ad4 = *(const float4*)(ad_ + (size_t)n * 4);
    for (int j = start + lane; j < end; j += 64){
        int s = csr[j];
        float4 as4 = *(const float4*)(as_ + (size_t)s * 4);
        float4 sc4 = *(const float4*)(sclb + (size_t)s * 4);
        float w0 = __expf(lrelu(as4.x + ad4.x));
        float w1 = __expf(lrelu(as4.y + ad4.y));
        float w2 = __expf(lrelu(as4.z + ad4.z));
        float w3 = __expf(lrelu(as4.w + ad4.w));
        uint4 o;
        o.x = (unsigned)f2b(w0) | ((unsigned)f2b(w0 * sc4.x) << 16);
        o.y = (unsigned)f2b(w1) | ((unsigned)f2b(w1 * sc4.y) << 16);
        o.z = (unsigned)f2b(w2) | ((unsigned)f2b(w2 * sc4.z) << 16);
        o.w = (unsigned)f2b(w3) | ((unsigned)f2b(w3 * sc4.w) << 16);
        *(uint4*)(wbuf + (size_t)j * 4) = o;
    }
}

// ---------------- lean aggregation on adaptive-int8 h: 1 wave/node, 8 ch/lane, depth-8 pipeline ----------------
// out[n] = elu((sum_j w_j*scl_j*q[src_j]) / (sum_j w_j) + bias); weights+scales precomputed in wbuf.
// Bounds logic wave-uniform (SALU); h address from readlane (SGPR). POOL computes x2 only.
template<bool POOL>
__global__ __launch_bounds__(256) void k_aggregate(const signed char* __restrict__ h,
    const int* __restrict__ offs, const int* __restrict__ csr,
    const unsigned* __restrict__ wbuf,
    const float* __restrict__ bias, ushort* __restrict__ out,
    const float* __restrict__ pw, const float* __restrict__ pb, float* __restrict__ x2){
    int wv   = threadIdx.x >> 6;
    int lane = threadIdx.x & 63;
    int n    = blockIdx.x * 4 + wv;       // one wave per node
    int cb   = lane * 8;                  // this lane's 8 channels
    int head = lane >> 4;
    int start = offs[n], end = offs[n + 1];
    const signed char* hrow = h + cb;     // int8: 1 B/channel
    float dsum = 0.f;
    float a0=0.f,a1=0.f,a2=0.f,a3=0.f,a4=0.f,a5=0.f,a6=0.f,a7=0.f;

    for (int base = start; base < end; base += 64){
        int bcnt = min(64, end - base);
        int pre = csr[base + min(lane, bcnt - 1)];   // 64 indices staged in regs
        unsigned wA0, wA1, wA2, wA3, wB0, wB1, wB2, wB3;
        uint2 hA0, hA1, hA2, hA3, hB0, hB1, hB2, hB3;

#define LOADE(W, H, E)                                                        \
        { int e_ = (E); int ec_ = min(e_, bcnt - 1);                          \
          int s_ = __builtin_amdgcn_readlane(pre, ec_);                       \
          unsigned wp_ = wbuf[(size_t)(base + ec_) * 4 + head];               \
          W = (e_ < bcnt) ? wp_ : 0u;                                         \
          H = *(const uint2*)(hrow + (size_t)s_ * HCdim); }

#define CONS(W, H)                                                            \
        { float w_  = bf2f((unsigned short)(W & 0xffff));                     \
          float ws_ = bf2f((unsigned short)(W >> 16));                        \
          dsum += w_;                                                         \
          int q0 = (int)(H.x << 24) >> 24;                                    \
          int q1 = (int)(H.x << 16) >> 24;                                    \
          int q2 = (int)(H.x <<  8) >> 24;                                    \
          int q3 = (int) H.x        >> 24;                                    \
          int q4 = (int)(H.y << 24) >> 24;                                    \
          int q5 = (int)(H.y << 16) >> 24;                                    \
          int q6 = (int)(H.y <<  8) >> 24;                                    \
          int q7 = (int) H.y        >> 24;                                    \
          a0 = fmaf(ws_, (float)q0, a0); a1 = fmaf(ws_, (float)q1, a1);       \
          a2 = fmaf(ws_, (float)q2, a2); a3 = fmaf(ws_, (float)q3, a3);       \
          a4 = fmaf(ws_, (float)q4, a4); a5 = fmaf(ws_, (float)q5, a5);       \
          a6 = fmaf(ws_, (float)q6, a6); a7 = fmaf(ws_, (float)q7, a7); }

        LOADE(wA0, hA0, 0) LOADE(wA1, hA1, 1) LOADE(wA2, hA2, 2) LOADE(wA3, hA3, 3)
        for (int g = 0; g < bcnt; g += 8){
            LOADE(wB0, hB0, g + 4) LOADE(wB1, hB1, g + 5)
            LOADE(wB2, hB2, g + 6) LOADE(wB3, hB3, g + 7)
            CONS(wA0, hA0) CONS(wA1, hA1) CONS(wA2, hA2) CONS(wA3, hA3)
            LOADE(wA0, hA0, g + 8) LOADE(wA1, hA1, g + 9)
            LOADE(wA2, hA2, g + 10) LOADE(wA3, hA3, g + 11)
            CONS(wB0, hB0) CONS(wB1, hB1) CONS(wB2, hB2) CONS(wB3, hB3)
        }
#undef LOADE
#undef CONS
    }
    float rden = 1.f / (dsum + 1e-16f);
    float4 b0 = *(const float4*)(bias + cb);
    float4 b1 = *(const float4*)(bias + cb + 4);
    float e0 = eluf(fmaf(a0, rden, b0.x));
    float e1 = eluf(fmaf(a1, rden, b0.y));
    float e2 = eluf(fmaf(a2, rden, b0.z));
    float e3 = eluf(fmaf(a3, rden, b0.w));
    float e4 = eluf(fmaf(a4, rden, b1.x));
    float e5 = eluf(fmaf(a5, rden, b1.y));
    float e6 = eluf(fmaf(a6, rden, b1.z));
    float e7 = eluf(fmaf(a7, rden, b1.w));
    if (!POOL){
        uint4 o;
        o.x = (unsigned)f2b(e0) | ((unsigned)f2b(e1) << 16);
        o.y = (unsigned)f2b(e2) | ((unsigned)f2b(e3) << 16);
        o.z = (unsigned)f2b(e4) | ((unsigned)f2b(e5) << 16);
        o.w = (unsigned)f2b(e6) | ((unsigned)f2b(e7) << 16);
        *(uint4*)(out + (size_t)n * HCdim + cb) = o;
    } else {
        float4 w0p = *(const float4*)(pw + cb);
        float4 w1p = *(const float4*)(pw + cb + 4);
        float s = e0*w0p.x + e1*w0p.y + e2*w0p.z + e3*w0p.w
                + e4*w1p.x + e5*w1p.y + e6*w1p.z + e7*w1p.w;
        #pragma unroll
        for (int off = 32; off; off >>= 1) s += __shfl_down(s, off);
        if (lane == 0) x2[n] = s + pb[0];
    }
}

// ---------------- fc1 with fused layernorm ----------------
__global__ __launch_bounds__(256) void k_fc1_ln(const float* __restrict__ x2,
    const float* __restrict__ lng, const float* __restrict__ lnb,
    const float* __restrict__ W, const float* __restrict__ bias,
    float* __restrict__ outms, float* __restrict__ e1b){
    __shared__ float xs[1024];
    __shared__ float red[4][64];
    __shared__ float red2[8];
    __shared__ float stats[2];
    int tid = threadIdx.x;
    int b = blockIdx.y, c0 = blockIdx.x * 64;
    float4 v = *(const float4*)(x2 + b * 1024 + tid * 4);
    float s  = v.x + v.y + v.z + v.w;
    float sq = v.x * v.x + v.y * v.y + v.z * v.z + v.w * v.w;
    #pragma unroll
    for (int off = 32; off; off >>= 1){ s += __shfl_down(s, off); sq += __shfl_down(sq, off); }
    if ((tid & 63) == 0){ red2[(tid >> 6) * 2] = s; red2[(tid >> 6) * 2 + 1] = sq; }
    __syncthreads();
    if (tid == 0){
        float S  = red2[0] + red2[2] + red2[4] + red2[6];
        float SQ = red2[1] + red2[3] + red2[5] + red2[7];
        float mu  = S * (1.f / 1024.f);
        float var = SQ * (1.f / 1024.f) - mu * mu;
        stats[0] = mu; stats[1] = rsqrtf(var + 1e-5f);
    }
    __syncthreads();
    float mu = stats[0], r = stats[1];
    float4 g4  = *(const float4*)(lng + tid * 4);
    float4 bb4 = *(const float4*)(lnb + tid * 4);
    float4 o;
    o.x = (v.x - mu) * r * g4.x + bb4.x;
    o.y = (v.y - mu) * r * g4.y + bb4.y;
    o.z = (v.z - mu) * r * g4.z + bb4.z;
    o.w = (v.w - mu) * r * g4.w + bb4.w;
    *(float4*)&xs[tid * 4] = o;
    if (blockIdx.x == 0) *(float4*)(outms + b * 1024 + tid * 4) = o;
    __syncthreads();
    int tx = tid & 63, ty = tid >> 6;
    const float* wp = W + (size_t)(ty * 256) * 512 + c0 + tx;
    float a = 0.f;
    #pragma unroll 8
    for (int i = 0; i < 256; i++)
        a = fmaf(xs[ty * 256 + i], wp[(size_t)i * 512], a);
    red[ty][tx] = a;
    __syncthreads();
    if (ty == 0){
        float vv = red[0][tx] + red[1][tx] + red[2][tx] + red[3][tx] + bias[c0 + tx];
        e1b[b * 512 + c0 + tx] = eluf(vv);
    }
}

// ---------------- FC layer ----------------
template<int K, int NOUT>
__global__ __launch_bounds__(256) void k_fc(const float* __restrict__ in,
    const float* __restrict__ W, const float* __restrict__ bias, float* __restrict__ outb){
    __shared__ float xs[K];
    __shared__ float red[4][64];
    int tid = threadIdx.x;
    int b = blockIdx.y, c0 = blockIdx.x * 64;
    int tx = tid & 63, ty = tid >> 6;
    for (int i = tid * 4; i < K; i += 1024)
        *(float4*)&xs[i] = *(const float4*)(in + b * K + i);
    __syncthreads();
    const float* wp = W + (size_t)(ty * (K / 4)) * NOUT + c0 + tx;
    float a = 0.f;
    #pragma unroll 8
    for (int i = 0; i < K / 4; i++)
        a = fmaf(xs[ty * (K / 4) + i], wp[(size_t)i * NOUT], a);
    red[ty][tx] = a;
    __syncthreads();
    if (ty == 0){
        float v = red[0][tx] + red[1][tx] + red[2][tx] + red[3][tx] + bias[c0 + tx];
        outb[b * NOUT + tx + c0] = eluf(v);
    }
}

// ---------------- final FC (128->64) + e output + pred ----------------
__global__ __launch_bounds__(256) void k_fc_final(const float* __restrict__ in,
    const float* __restrict__ W, const float* __restrict__ bias,
    const float* __restrict__ lw, const float* __restrict__ lb, float* __restrict__ out){
    __shared__ float xs[128];
    __shared__ float red[4][64];
    __shared__ float evs[64];
    int tid = threadIdx.x;
    int b = blockIdx.x;
    int tx = tid & 63, ty = tid >> 6;
    if (tid * 4 < 128)
        *(float4*)&xs[tid * 4] = *(const float4*)(in + b * 128 + tid * 4);
    __syncthreads();
    const float* wp = W + (size_t)(ty * 32) * 64 + tx;
    float a = 0.f;
    #pragma unroll
    for (int i = 0; i < 32; i++)
        a = fmaf(xs[ty * 32 + i], wp[(size_t)i * 64], a);
    red[ty][tx] = a;
    __syncthreads();
    if (ty == 0){
        float ev = eluf(red[0][tx] + red[1][tx] + red[2][tx] + red[3][tx] + bias[tx]);
        evs[tx] = ev;
        out[16384 + b * 64 + tx] = ev;
    }
    __syncthreads();
    if (ty == 0){
        float p = evs[tx] * lw[tx];
        #pragma unroll
        for (int off = 32; off; off >>= 1) p += __shfl_down(p, off);
        if (tx == 0) out[16384 + 1024 + b] = p + lb[0];
    }
}

extern "C" void kernel_launch(void* const* d_in, const int* in_sizes, int n_in,
                              void* d_out, int out_size, void* d_ws, size_t ws_size,
                              hipStream_t stream) {
    const float* x        = (const float*)d_in[0];
    const int*   ei       = (const int*)  d_in[1];
    const float* W1       = (const float*)d_in[3];
    const float* att_src1 = (const float*)d_in[4];
    const float* att_dst1 = (const float*)d_in[5];
    const float* b1       = (const float*)d_in[6];
    const float* W2       = (const float*)d_in[7];
    const float* att_src2 = (const float*)d_in[8];
    const float* att_dst2 = (const float*)d_in[9];
    const float* b2       = (const float*)d_in[10];
    const float* p2w      = (const float*)d_in[13];
    const float* p2b      = (const float*)d_in[14];
    const float* ln_g     = (const float*)d_in[15];
    const float* ln_b     = (const float*)d_in[16];
    const float* fw1      = (const float*)d_in[17];
    const float* fb1      = (const float*)d_in[18];
    const float* fw2      = (const float*)d_in[19];
    const float* fb2      = (const float*)d_in[20];
    const float* fw3      = (const float*)d_in[21];
    const float* fb3      = (const float*)d_in[22];
    const float* fw4      = (const float*)d_in[23];
    const float* fb4      = (const float*)d_in[24];
    const float* lw       = (const float*)d_in[25];
    const float* lb       = (const float*)d_in[26];
    float* out = (float*)d_out;

    // workspace layout (bytes), ~50.2 MB total
    char* w = (char*)d_ws;
    ushort* xb   = (ushort*)(w);                 // 32 MB; h1b (16 MB) reuses after GEMM1
    ushort* h1b  = (ushort*)(w);
    signed char* hpre = (signed char*)(w + 33554432);  // 8 MB int8 (both layers, sequential)
    ushort* W1T  = (ushort*)(w + 41943040);      // 1 MB
    ushort* W2T  = (ushort*)(w + 42991616);      // 0.5 MB
    float* asb   = (float*)(w + 43515904);       // 256 KB
    float* adb   = (float*)(w + 43778048);       // 256 KB
    float* sclb  = (float*)(w + 44040192);       // 256 KB
    int*   deg   = (int*)  (w + 44302336);       // 64 KB
    int*   cursor= (int*)  (w + 44367872);       // 64 KB
    int*   offs  = (int*)  (w + 44433408);       // 64 KB + 4
    int*   csr   = (int*)  (w + 44499200);       // 1.06 MB
    unsigned* wbuf = (unsigned*)(w + 45613312);  // EP_*16 = 4.25 MB
    float* x2b   = (float*)(w + 50069760);       // 64 KB
    float* e1b   = (float*)(w + 50135296);       // 32 KB
    float* e2b   = (float*)(w + 50167808);       // 16 KB
    float* e3b   = (float*)(w + 50184192);       // 8 KB

    // ---- CSR build ----
    k_zero_i <<<(2 * NN + 255) / 256, 256, 0, stream>>>(deg, 2 * NN);
    k_degree <<<(EP_ + 255) / 256, 256, 0, stream>>>(ei, deg);
    k_scan   <<<1, 1024, 0, stream>>>(deg, offs);
    k_scatter<<<(EP_ + 255) / 256, 256, 0, stream>>>(ei, offs, cursor, csr);

    // ---- casts (merged) ----
    k_casts<<<16384 + 512 + 256, 256, 0, stream>>>(x, xb, W1, W1T, W2, W2T);

    dim3 ggrid(HCdim / 128, NN / 64);   // (4, 256) = 1024 blocks, 4/CU
    // ---- GAT layer 1 (adaptive-int8 h staging) ----
    gemm_bf16         <<<ggrid, 256, 0, stream>>>(xb, W1T, hpre, att_src1, att_dst1,
                                                  asb, adb, sclb, NN, HCdim, DIN);
    k_edgew           <<<NN / 4, 256, 0, stream>>>(offs, csr, asb, adb, sclb, wbuf);
    k_aggregate<false><<<NN / 4, 256, 0, stream>>>(hpre, offs, csr, wbuf, b1, h1b,
                                                   nullptr, nullptr, nullptr);
    // ---- GAT layer 2 (adaptive-int8 h staging; pool fused, h2 store skipped) ----
    gemm_bf16         <<<ggrid, 256, 0, stream>>>(h1b, W2T, hpre, att_src2, att_dst2,
                                                  asb, adb, sclb, NN, HCdim, HCdim);
    k_edgew           <<<NN / 4, 256, 0, stream>>>(offs, csr, asb, adb, sclb, wbuf);
    k_aggregate<true> <<<NN / 4, 256, 0, stream>>>(hpre, offs, csr, wbuf, b2, nullptr,
                                                   p2w, p2b, x2b);
    // ---- encoder MLP (LN fused into fc1; split tail) ----
    k_fc1_ln          <<<dim3(8, 16), 256, 0, stream>>>(x2b, ln_g, ln_b, fw1, fb1, out, e1b);
    k_fc< 512, 256>   <<<dim3(4, 16), 256, 0, stream>>>(e1b, fw2, fb2, e2b);
    k_fc< 256, 128>   <<<dim3(2, 16), 256, 0, stream>>>(e2b, fw3, fb3, e3b);
    k_fc_final        <<<16, 256, 0, stream>>>(e3b, fw4, fb4, lw, lb, out);
}

// Round 12
// 347.253 us; speedup vs baseline: 1.0189x; 1.0189x over previous
//
#include <hip/hip_runtime.h>
#include <math.h>

#define NN    16384     // nodes
#define DIN   1024
#define HCdim 512       // H*C
#define NHEAD 4
#define NE_   262144    // edges (without self loops)
#define EP_   (NE_ + NN) // with self loops

using short8  = __attribute__((ext_vector_type(8))) short;
using floatx4 = __attribute__((ext_vector_type(4))) float;

typedef __attribute__((address_space(3))) unsigned int lds_uint;
typedef const __attribute__((address_space(1))) unsigned int glb_uint;
#define ASYNC_LD16(g, l) __builtin_amdgcn_global_load_lds((glb_uint*)(g), (lds_uint*)(l), 16, 0, 0)

__device__ __forceinline__ float eluf(float x){ return x > 0.f ? x : expm1f(x); }
__device__ __forceinline__ float lrelu(float x){ return x > 0.f ? x : 0.2f * x; }
__device__ __forceinline__ float bf2f(unsigned short u){
    union { unsigned int i; float f; } c; c.i = ((unsigned int)u) << 16; return c.f;
}
__device__ __forceinline__ unsigned short f2b(float f){
    union { float f; unsigned int u; } c; c.f = f;
    unsigned int u = c.u;
    return (unsigned short)((u + 0x7FFFu + ((u >> 16) & 1u)) >> 16);   // RNE
}

// ---------------- CSR build ----------------
__global__ void k_zero_i(int* __restrict__ p, int n){
    int i = blockIdx.x * 256 + threadIdx.x;
    if (i < n) p[i] = 0;
}

__global__ void k_degree(const int* __restrict__ ei, int* __restrict__ deg){
    int i = blockIdx.x * 256 + threadIdx.x;
    if (i >= EP_) return;
    int d = (i < NE_) ? ei[NE_ + i] : (i - NE_);
    atomicAdd(&deg[d], 1);
}

__global__ __launch_bounds__(1024) void k_scan(const int* __restrict__ deg, int* __restrict__ offs){
    __shared__ int s[1024];
    int tid  = threadIdx.x;
    int base = tid * 16;
    int local[16];
    int sum = 0;
    #pragma unroll
    for (int i = 0; i < 16; i++){ local[i] = deg[base + i]; sum += local[i]; }
    s[tid] = sum;
    __syncthreads();
    for (int off = 1; off < 1024; off <<= 1){
        int v = (tid >= off) ? s[tid - off] : 0;
        __syncthreads();
        s[tid] += v;
        __syncthreads();
    }
    int run = (tid == 0) ? 0 : s[tid - 1];
    #pragma unroll
    for (int i = 0; i < 16; i++){ offs[base + i] = run; run += local[i]; }
    if (tid == 1023) offs[NN] = run;
}

__global__ void k_scatter(const int* __restrict__ ei, const int* __restrict__ offs,
                          int* __restrict__ cursor, int* __restrict__ csr){
    int i = blockIdx.x * 256 + threadIdx.x;
    if (i >= EP_) return;
    int srcv, dstv;
    if (i < NE_){ srcv = ei[i]; dstv = ei[NE_ + i]; }
    else        { srcv = dstv = i - NE_; }
    int pos = offs[dstv] + atomicAdd(&cursor[dstv], 1);
    csr[pos] = srcv;
}

// ---------------- merged casts: x -> bf16 ; W1,W2 -> bf16 transposed ----------------
__global__ __launch_bounds__(256) void k_casts(const float* __restrict__ x, ushort* __restrict__ xb,
    const float* __restrict__ W1, ushort* __restrict__ W1T,
    const float* __restrict__ W2, ushort* __restrict__ W2T){
    int bid = blockIdx.x, tid = threadIdx.x;
    if (bid < 16384){
        int i = bid * 256 + tid;
        float4 v = *(const float4*)(x + (size_t)i * 4);
        ushort4 o = { f2b(v.x), f2b(v.y), f2b(v.z), f2b(v.w) };
        *(ushort4*)(xb + (size_t)i * 4) = o;
    } else if (bid < 16384 + 512){
        int t = (bid - 16384) * 256 + tid;          // W1: 1024x512 -> T
        int n = t >> 8, kb = (t & 255) * 4;
        ushort4 o = { f2b(W1[(size_t)(kb+0)*HCdim + n]), f2b(W1[(size_t)(kb+1)*HCdim + n]),
                      f2b(W1[(size_t)(kb+2)*HCdim + n]), f2b(W1[(size_t)(kb+3)*HCdim + n]) };
        *(ushort4*)(W1T + (size_t)n * DIN + kb) = o;
    } else {
        int t = (bid - 16896) * 256 + tid;          // W2: 512x512 -> T
        int n = t >> 7, kb = (t & 127) * 4;
        ushort4 o = { f2b(W2[(size_t)(kb+0)*HCdim + n]), f2b(W2[(size_t)(kb+1)*HCdim + n]),
                      f2b(W2[(size_t)(kb+2)*HCdim + n]), f2b(W2[(size_t)(kb+3)*HCdim + n]) };
        *(ushort4*)(W2T + (size_t)n * HCdim + kb) = o;
    }
}

// ---------------- bf16 MFMA GEMM (64x128 tile, BK=64 via 2 regions) -> adaptive int8 C ----------------
// C[M,512] = A[M,K] @ BT[512,K]^T, stored int8 with scl[node][head] = absmax/127.
// grid(M/64, 4): blockIdx.x = node-row (fast dim) => all 4 heads of a row land on the SAME XCD
// (id = row + 256*head, 256 % 8 == 0) -> A-rows fetched from HBM once, shared via that XCD's L2.
// BK=64 as two BK=32 LDS regions (keeps global_load_lds linear-dest AND 8-way-max read stride);
// one barrier pair per 64 K => half the vmcnt(0) drains.
__global__ __launch_bounds__(256) void gemm_bf16(const ushort* __restrict__ A,
                                                 const ushort* __restrict__ BT,
                                                 signed char* __restrict__ C,
                                                 const float* __restrict__ att_s,
                                                 const float* __restrict__ att_d,
                                                 float* __restrict__ as_, float* __restrict__ ad_,
                                                 float* __restrict__ sclb,
                                                 int M, int Nn, int K){
    __shared__ ushort As[2][64 * 32];
    __shared__ ushort Bs[2][128 * 32];
    __shared__ float prS[2][64];
    __shared__ float prD[2][64];
    __shared__ float amx[2][64];
    int tid = threadIdx.x;
    int m0 = blockIdx.x * 64, n0 = blockIdx.y * 128;
    int cx = blockIdx.y;                 // head
    int lane = tid & 63, w = tid >> 6;
    int wm = (w >> 1) * 32, wn = (w & 1) * 64;   // wm: node offset (0/32), wn: channel offset (0/64)
    int la = lane & 15, qd = lane >> 4;

    int srow = tid >> 2, schunk = (tid & 3) * 8;   // srow 0..63
    const ushort* Ag = A  + (size_t)(m0 + srow) * K + schunk;
    const ushort* Bg = BT + (size_t)(n0 + srow) * K + schunk;
    ushort* Asw0 = &As[0][srow * 32 + schunk];
    ushort* Asw1 = &As[1][srow * 32 + schunk];
    ushort* Bsw0 = &Bs[0][srow * 32 + schunk];
    ushort* Bsw1 = &Bs[1][srow * 32 + schunk];

    floatx4 acc[4][2] = {};   // acc[i=channel-block<4][j=node-block<2]
    for (int k0 = 0; k0 < K; k0 += 64){
        __syncthreads();
        ASYNC_LD16(Ag + k0,                       Asw0);
        ASYNC_LD16(Ag + k0 + 32,                  Asw1);
        ASYNC_LD16(Bg + k0,                       Bsw0);
        ASYNC_LD16(Bg + (size_t)64 * K + k0,      Bsw0 + 64 * 32);
        ASYNC_LD16(Bg + k0 + 32,                  Bsw1);
        ASYNC_LD16(Bg + (size_t)64 * K + k0 + 32, Bsw1 + 64 * 32);
        __syncthreads();
        #pragma unroll
        for (int kk = 0; kk < 2; kk++){
            short8 af[2], bf[4];
            #pragma unroll
            for (int j = 0; j < 2; j++)
                af[j] = *(const short8*)&As[kk][(wm + j*16 + la) * 32 + qd * 8];  // nodes
            #pragma unroll
            for (int i = 0; i < 4; i++)
                bf[i] = *(const short8*)&Bs[kk][(wn + i*16 + la) * 32 + qd * 8];  // channels
            #pragma unroll
            for (int i = 0; i < 4; i++)
                #pragma unroll
                for (int j = 0; j < 2; j++)
                    acc[i][j] = __builtin_amdgcn_mfma_f32_16x16x32_bf16(bf[i], af[j], acc[i][j], 0, 0, 0);
        }
    }
    // attention partials: lane's channels = wn + i*16 + qd*4 + r ; node = wm + j*16 + la
    float4 s4[4], d4[4];
    #pragma unroll
    for (int i = 0; i < 4; i++){
        s4[i] = *(const float4*)(att_s + cx * 128 + wn + i * 16 + qd * 4);
        d4[i] = *(const float4*)(att_d + cx * 128 + wn + i * 16 + qd * 4);
    }
    int half = wn >> 6;
    #pragma unroll
    for (int j = 0; j < 2; j++){
        float ps = 0.f, pd = 0.f;
        #pragma unroll
        for (int i = 0; i < 4; i++){
            ps = fmaf(acc[i][j][0], s4[i].x, ps); pd = fmaf(acc[i][j][0], d4[i].x, pd);
            ps = fmaf(acc[i][j][1], s4[i].y, ps); pd = fmaf(acc[i][j][1], d4[i].y, pd);
            ps = fmaf(acc[i][j][2], s4[i].z, ps); pd = fmaf(acc[i][j][2], d4[i].z, pd);
            ps = fmaf(acc[i][j][3], s4[i].w, ps); pd = fmaf(acc[i][j][3], d4[i].w, pd);
        }
        ps += __shfl_xor(ps, 16); ps += __shfl_xor(ps, 32);
        pd += __shfl_xor(pd, 16); pd += __shfl_xor(pd, 32);
        // per-node absmax over this wave's 64 channels
        float am = 0.f;
        #pragma unroll
        for (int i = 0; i < 4; i++){
            am = fmaxf(am, fabsf(acc[i][j][0])); am = fmaxf(am, fabsf(acc[i][j][1]));
            am = fmaxf(am, fabsf(acc[i][j][2])); am = fmaxf(am, fabsf(acc[i][j][3]));
        }
        am = fmaxf(am, __shfl_xor(am, 16)); am = fmaxf(am, __shfl_xor(am, 32));
        if (lane < 16){            // qd == 0 holds full reductions
            prS[half][wm + j * 16 + la] = ps;
            prD[half][wm + j * 16 + la] = pd;
            amx[half][wm + j * 16 + la] = am;
        }
    }
    __syncthreads();
    // quantized C store: node = m0+wm+j*16+la, channels n0+wn+i*16+qd*4 .. +3
    #pragma unroll
    for (int j = 0; j < 2; j++){
        int nl = wm + j * 16 + la;
        float amax = fmaxf(fmaxf(amx[0][nl], amx[1][nl]), 1e-20f);
        float inv = 127.0f / amax;
        #pragma unroll
        for (int i = 0; i < 4; i++){
            int q0 = (int)rintf(acc[i][j][0] * inv);
            int q1 = (int)rintf(acc[i][j][1] * inv);
            int q2 = (int)rintf(acc[i][j][2] * inv);
            int q3 = (int)rintf(acc[i][j][3] * inv);
            unsigned pk = (q0 & 0xff) | ((q1 & 0xff) << 8) | ((q2 & 0xff) << 16) | ((q3 & 0xff) << 24);
            *(unsigned*)(C + (size_t)(m0 + nl) * HCdim + n0 + wn + i * 16 + qd * 4) = pk;
        }
    }
    if (tid < 64){
        as_[(size_t)(m0 + tid) * 4 + cx]  = prS[0][tid] + prS[1][tid];
        ad_[(size_t)(m0 + tid) * 4 + cx]  = prD[0][tid] + prD[1][tid];
        sclb[(size_t)(m0 + tid) * 4 + cx] = fmaxf(fmaxf(amx[0][tid], amx[1][tid]), 1e-20f) * (1.f / 127.f);
    }
}

// ---------------- edge weights: wbuf[j][h] = {bf16 w, bf16 w*scl[src][h]} packed in uint ----------------
__global__ __launch_bounds__(256) void k_edgew(const int* __restrict__ offs, const int* __restrict__ csr,
    const float* __restrict__ as_, const float* __restrict__ ad_,
    const float* __restrict__ sclb, unsigned* __restrict__ wbuf){
    int wv = threadIdx.x >> 6, lane = threadIdx.x & 63;
    int n = blockIdx.x * 4 + wv;
    int start = offs[n], end = offs[n + 1];
    float4 ad4 = *(const float4*)(ad_ + (size_t)n * 4);
    for (int j = start + lane; j < end; j += 64){
        int s = csr[j];
        float4 as4 = *(const float4*)(as_ + (size_t)s * 4);
        float4 sc4 = *(const float4*)(sclb + (size_t)s * 4);
        float w0 = __expf(lrelu(as4.x + ad4.x));
        float w1 = __expf(lrelu(as4.y + ad4.y));
        float w2 = __expf(lrelu(as4.z + ad4.z));
        float w3 = __expf(lrelu(as4.w + ad4.w));
        uint4 o;
        o.x = (unsigned)f2b(w0) | ((unsigned)f2b(w0 * sc4.x) << 16);
        o.y = (unsigned)f2b(w1) | ((unsigned)f2b(w1 * sc4.y) << 16);
        o.z = (unsigned)f2b(w2) | ((unsigned)f2b(w2 * sc4.z) << 16);
        o.w = (unsigned)f2b(w3) | ((unsigned)f2b(w3 * sc4.w) << 16);
        *(uint4*)(wbuf + (size_t)j * 4) = o;
    }
}

// ---------------- lean aggregation on adaptive-int8 h: 1 wave/node, 8 ch/lane, depth-8 pipeline ----------------
// out[n] = elu((sum_j w_j*scl_j*q[src_j]) / (sum_j w_j) + bias); weights+scales precomputed in wbuf.
// Bounds logic wave-uniform (SALU); h address from readlane (SGPR). POOL computes x2 only.
template<bool POOL>
__global__ __launch_bounds__(256) void k_aggregate(const signed char* __restrict__ h,
    const int* __restrict__ offs, const int* __restrict__ csr,
    const unsigned* __restrict__ wbuf,
    const float* __restrict__ bias, ushort* __restrict__ out,
    const float* __restrict__ pw, const float* __restrict__ pb, float* __restrict__ x2){
    int wv   = threadIdx.x >> 6;
    int lane = threadIdx.x & 63;
    int n    = blockIdx.x * 4 + wv;       // one wave per node
    int cb   = lane * 8;                  // this lane's 8 channels
    int head = lane >> 4;
    int start = offs[n], end = offs[n + 1];
    const signed char* hrow = h + cb;     // int8: 1 B/channel
    float dsum = 0.f;
    float a0=0.f,a1=0.f,a2=0.f,a3=0.f,a4=0.f,a5=0.f,a6=0.f,a7=0.f;

    for (int base = start; base < end; base += 64){
        int bcnt = min(64, end - base);
        int pre = csr[base + min(lane, bcnt - 1)];   // 64 indices staged in regs
        unsigned wA0, wA1, wA2, wA3, wB0, wB1, wB2, wB3;
        uint2 hA0, hA1, hA2, hA3, hB0, hB1, hB2, hB3;

#define LOADE(W, H, E)                                                        \
        { int e_ = (E); int ec_ = min(e_, bcnt - 1);                          \
          int s_ = __builtin_amdgcn_readlane(pre, ec_);                       \
          unsigned wp_ = wbuf[(size_t)(base + ec_) * 4 + head];               \
          W = (e_ < bcnt) ? wp_ : 0u;                                         \
          H = *(const uint2*)(hrow + (size_t)s_ * HCdim); }

#define CONS(W, H)                                                            \
        { float w_  = bf2f((unsigned short)(W & 0xffff));                     \
          float ws_ = bf2f((unsigned short)(W >> 16));                        \
          dsum += w_;                                                         \
          int q0 = (int)(H.x << 24) >> 24;                                    \
          int q1 = (int)(H.x << 16) >> 24;                                    \
          int q2 = (int)(H.x <<  8) >> 24;                                    \
          int q3 = (int) H.x        >> 24;                                    \
          int q4 = (int)(H.y << 24) >> 24;                                    \
          int q5 = (int)(H.y << 16) >> 24;                                    \
          int q6 = (int)(H.y <<  8) >> 24;                                    \
          int q7 = (int) H.y        >> 24;                                    \
          a0 = fmaf(ws_, (float)q0, a0); a1 = fmaf(ws_, (float)q1, a1);       \
          a2 = fmaf(ws_, (float)q2, a2); a3 = fmaf(ws_, (float)q3, a3);       \
          a4 = fmaf(ws_, (float)q4, a4); a5 = fmaf(ws_, (float)q5, a5);       \
          a6 = fmaf(ws_, (float)q6, a6); a7 = fmaf(ws_, (float)q7, a7); }

        LOADE(wA0, hA0, 0) LOADE(wA1, hA1, 1) LOADE(wA2, hA2, 2) LOADE(wA3, hA3, 3)
        for (int g = 0; g < bcnt; g += 8){
            LOADE(wB0, hB0, g + 4) LOADE(wB1, hB1, g + 5)
            LOADE(wB2, hB2, g + 6) LOADE(wB3, hB3, g + 7)
            CONS(wA0, hA0) CONS(wA1, hA1) CONS(wA2, hA2) CONS(wA3, hA3)
            LOADE(wA0, hA0, g + 8) LOADE(wA1, hA1, g + 9)
            LOADE(wA2, hA2, g + 10) LOADE(wA3, hA3, g + 11)
            CONS(wB0, hB0) CONS(wB1, hB1) CONS(wB2, hB2) CONS(wB3, hB3)
        }
#undef LOADE
#undef CONS
    }
    float rden = 1.f / (dsum + 1e-16f);
    float4 b0 = *(const float4*)(bias + cb);
    float4 b1 = *(const float4*)(bias + cb + 4);
    float e0 = eluf(fmaf(a0, rden, b0.x));
    float e1 = eluf(fmaf(a1, rden, b0.y));
    float e2 = eluf(fmaf(a2, rden, b0.z));
    float e3 = eluf(fmaf(a3, rden, b0.w));
    float e4 = eluf(fmaf(a4, rden, b1.x));
    float e5 = eluf(fmaf(a5, rden, b1.y));
    float e6 = eluf(fmaf(a6, rden, b1.z));
    float e7 = eluf(fmaf(a7, rden, b1.w));
    if (!POOL){
        uint4 o;
        o.x = (unsigned)f2b(e0) | ((unsigned)f2b(e1) << 16);
        o.y = (unsigned)f2b(e2) | ((unsigned)f2b(e3) << 16);
        o.z = (unsigned)f2b(e4) | ((unsigned)f2b(e5) << 16);
        o.w = (unsigned)f2b(e6) | ((unsigned)f2b(e7) << 16);
        *(uint4*)(out + (size_t)n * HCdim + cb) = o;
    } else {
        float4 w0p = *(const float4*)(pw + cb);
        float4 w1p = *(const float4*)(pw + cb + 4);
        float s = e0*w0p.x + e1*w0p.y + e2*w0p.z + e3*w0p.w
                + e4*w1p.x + e5*w1p.y + e6*w1p.z + e7*w1p.w;
        #pragma unroll
        for (int off = 32; off; off >>= 1) s += __shfl_down(s, off);
        if (lane == 0) x2[n] = s + pb[0];
    }
}

// ---------------- fc1 with fused layernorm ----------------
__global__ __launch_bounds__(256) void k_fc1_ln(const float* __restrict__ x2,
    const float* __restrict__ lng, const float* __restrict__ lnb,
    const float* __restrict__ W, const float* __restrict__ bias,
    float* __restrict__ outms, float* __restrict__ e1b){
    __shared__ float xs[1024];
    __shared__ float red[4][64];
    __shared__ float red2[8];
    __shared__ float stats[2];
    int tid = threadIdx.x;
    int b = blockIdx.y, c0 = blockIdx.x * 64;
    float4 v = *(const float4*)(x2 + b * 1024 + tid * 4);
    float s  = v.x + v.y + v.z + v.w;
    float sq = v.x * v.x + v.y * v.y + v.z * v.z + v.w * v.w;
    #pragma unroll
    for (int off = 32; off; off >>= 1){ s += __shfl_down(s, off); sq += __shfl_down(sq, off); }
    if ((tid & 63) == 0){ red2[(tid >> 6) * 2] = s; red2[(tid >> 6) * 2 + 1] = sq; }
    __syncthreads();
    if (tid == 0){
        float S  = red2[0] + red2[2] + red2[4] + red2[6];
        float SQ = red2[1] + red2[3] + red2[5] + red2[7];
        float mu  = S * (1.f / 1024.f);
        float var = SQ * (1.f / 1024.f) - mu * mu;
        stats[0] = mu; stats[1] = rsqrtf(var + 1e-5f);
    }
    __syncthreads();
    float mu = stats[0], r = stats[1];
    float4 g4  = *(const float4*)(lng + tid * 4);
    float4 bb4 = *(const float4*)(lnb + tid * 4);
    float4 o;
    o.x = (v.x - mu) * r * g4.x + bb4.x;
    o.y = (v.y - mu) * r * g4.y + bb4.y;
    o.z = (v.z - mu) * r * g4.z + bb4.z;
    o.w = (v.w - mu) * r * g4.w + bb4.w;
    *(float4*)&xs[tid * 4] = o;
    if (blockIdx.x == 0) *(float4*)(outms + b * 1024 + tid * 4) = o;
    __syncthreads();
    int tx = tid & 63, ty = tid >> 6;
    const float* wp = W + (size_t)(ty * 256) * 512 + c0 + tx;
    float a = 0.f;
    #pragma unroll 8
    for (int i = 0; i < 256; i++)
        a = fmaf(xs[ty * 256 + i], wp[(size_t)i * 512], a);
    red[ty][tx] = a;
    __syncthreads();
    if (ty == 0){
        float vv = red[0][tx] + red[1][tx] + red[2][tx] + red[3][tx] + bias[c0 + tx];
        e1b[b * 512 + c0 + tx] = eluf(vv);
    }
}

// ---------------- FC layer ----------------
template<int K, int NOUT>
__global__ __launch_bounds__(256) void k_fc(const float* __restrict__ in,
    const float* __restrict__ W, const float* __restrict__ bias, float* __restrict__ outb){
    __shared__ float xs[K];
    __shared__ float red[4][64];
    int tid = threadIdx.x;
    int b = blockIdx.y, c0 = blockIdx.x * 64;
    int tx = tid & 63, ty = tid >> 6;
    for (int i = tid * 4; i < K; i += 1024)
        *(float4*)&xs[i] = *(const float4*)(in + b * K + i);
    __syncthreads();
    const float* wp = W + (size_t)(ty * (K / 4)) * NOUT + c0 + tx;
    float a = 0.f;
    #pragma unroll 8
    for (int i = 0; i < K / 4; i++)
        a = fmaf(xs[ty * (K / 4) + i], wp[(size_t)i * NOUT], a);
    red[ty][tx] = a;
    __syncthreads();
    if (ty == 0){
        float v = red[0][tx] + red[1][tx] + red[2][tx] + red[3][tx] + bias[c0 + tx];
        outb[b * NOUT + tx + c0] = eluf(v);
    }
}

// ---------------- final FC (128->64) + e output + pred ----------------
__global__ __launch_bounds__(256) void k_fc_final(const float* __restrict__ in,
    const float* __restrict__ W, const float* __restrict__ bias,
    const float* __restrict__ lw, const float* __restrict__ lb, float* __restrict__ out){
    __shared__ float xs[128];
    __shared__ float red[4][64];
    __shared__ float evs[64];
    int tid = threadIdx.x;
    int b = blockIdx.x;
    int tx = tid & 63, ty = tid >> 6;
    if (tid * 4 < 128)
        *(float4*)&xs[tid * 4] = *(const float4*)(in + b * 128 + tid * 4);
    __syncthreads();
    const float* wp = W + (size_t)(ty * 32) * 64 + tx;
    float a = 0.f;
    #pragma unroll
    for (int i = 0; i < 32; i++)
        a = fmaf(xs[ty * 32 + i], wp[(size_t)i * 64], a);
    red[ty][tx] = a;
    __syncthreads();
    if (ty == 0){
        float ev = eluf(red[0][tx] + red[1][tx] + red[2][tx] + red[3][tx] + bias[tx]);
        evs[tx] = ev;
        out[16384 + b * 64 + tx] = ev;
    }
    __syncthreads();
    if (ty == 0){
        float p = evs[tx] * lw[tx];
        #pragma unroll
        for (int off = 32; off; off >>= 1) p += __shfl_down(p, off);
        if (tx == 0) out[16384 + 1024 + b] = p + lb[0];
    }
}

extern "C" void kernel_launch(void* const* d_in, const int* in_sizes, int n_in,
                              void* d_out, int out_size, void* d_ws, size_t ws_size,
                              hipStream_t stream) {
    const float* x        = (const float*)d_in[0];
    const int*   ei       = (const int*)  d_in[1];
    const float* W1       = (const float*)d_in[3];
    const float* att_src1 = (const float*)d_in[4];
    const float* att_dst1 = (const float*)d_in[5];
    const float* b1       = (const float*)d_in[6];
    const float* W2       = (const float*)d_in[7];
    const float* att_src2 = (const float*)d_in[8];
    const float* att_dst2 = (const float*)d_in[9];
    const float* b2       = (const float*)d_in[10];
    const float* p2w      = (const float*)d_in[13];
    const float* p2b      = (const float*)d_in[14];
    const float* ln_g     = (const float*)d_in[15];
    const float* ln_b     = (const float*)d_in[16];
    const float* fw1      = (const float*)d_in[17];
    const float* fb1      = (const float*)d_in[18];
    const float* fw2      = (const float*)d_in[19];
    const float* fb2      = (const float*)d_in[20];
    const float* fw3      = (const float*)d_in[21];
    const float* fb3      = (const float*)d_in[22];
    const float* fw4      = (const float*)d_in[23];
    const float* fb4      = (const float*)d_in[24];
    const float* lw       = (const float*)d_in[25];
    const float* lb       = (const float*)d_in[26];
    float* out = (float*)d_out;

    // workspace layout (bytes), ~50.2 MB total
    char* w = (char*)d_ws;
    ushort* xb   = (ushort*)(w);                 // 32 MB; h1b (16 MB) reuses after GEMM1
    ushort* h1b  = (ushort*)(w);
    signed char* hpre = (signed char*)(w + 33554432);  // 8 MB int8 (both layers, sequential)
    ushort* W1T  = (ushort*)(w + 41943040);      // 1 MB
    ushort* W2T  = (ushort*)(w + 42991616);      // 0.5 MB
    float* asb   = (float*)(w + 43515904);       // 256 KB
    float* adb   = (float*)(w + 43778048);       // 256 KB
    float* sclb  = (float*)(w + 44040192);       // 256 KB
    int*   deg   = (int*)  (w + 44302336);       // 64 KB
    int*   cursor= (int*)  (w + 44367872);       // 64 KB
    int*   offs  = (int*)  (w + 44433408);       // 64 KB + 4
    int*   csr   = (int*)  (w + 44499200);       // 1.06 MB
    unsigned* wbuf = (unsigned*)(w + 45613312);  // EP_*16 = 4.25 MB
    float* x2b   = (float*)(w + 50069760);       // 64 KB
    float* e1b   = (float*)(w + 50135296);       // 32 KB
    float* e2b   = (float*)(w + 50167808);       // 16 KB
    float* e3b   = (float*)(w + 50184192);       // 8 KB

    // ---- CSR build ----
    k_zero_i <<<(2 * NN + 255) / 256, 256, 0, stream>>>(deg, 2 * NN);
    k_degree <<<(EP_ + 255) / 256, 256, 0, stream>>>(ei, deg);
    k_scan   <<<1, 1024, 0, stream>>>(deg, offs);
    k_scatter<<<(EP_ + 255) / 256, 256, 0, stream>>>(ei, offs, cursor, csr);

    // ---- casts (merged) ----
    k_casts<<<16384 + 512 + 256, 256, 0, stream>>>(x, xb, W1, W1T, W2, W2T);

    dim3 ggrid(NN / 64, HCdim / 128);   // (256, 4): node-row fast => same-row heads share XCD
    // ---- GAT layer 1 (adaptive-int8 h staging) ----
    gemm_bf16         <<<ggrid, 256, 0, stream>>>(xb, W1T, hpre, att_src1, att_dst1,
                                                  asb, adb, sclb, NN, HCdim, DIN);
    k_edgew           <<<NN / 4, 256, 0, stream>>>(offs, csr, asb, adb, sclb, wbuf);
    k_aggregate<false><<<NN / 4, 256, 0, stream>>>(hpre, offs, csr, wbuf, b1, h1b,
                                                   nullptr, nullptr, nullptr);
    // ---- GAT layer 2 (adaptive-int8 h staging; pool fused, h2 store skipped) ----
    gemm_bf16         <<<ggrid, 256, 0, stream>>>(h1b, W2T, hpre, att_src2, att_dst2,
                                                  asb, adb, sclb, NN, HCdim, HCdim);
    k_edgew           <<<NN / 4, 256, 0, stream>>>(offs, csr, asb, adb, sclb, wbuf);
    k_aggregate<true> <<<NN / 4, 256, 0, stream>>>(hpre, offs, csr, wbuf, b2, nullptr,
                                                   p2w, p2b, x2b);
    // ---- encoder MLP (LN fused into fc1; split tail) ----
    k_fc1_ln          <<<dim3(8, 16), 256, 0, stream>>>(x2b, ln_g, ln_b, fw1, fb1, out, e1b);
    k_fc< 512, 256>   <<<dim3(4, 16), 256, 0, stream>>>(e1b, fw2, fb2, e2b);
    k_fc< 256, 128>   <<<dim3(2, 16), 256, 0, stream>>>(e2b, fw3, fb3, e3b);
    k_fc_final        <<<16, 256, 0, stream>>>(e3b, fw4, fb4, lw, lb, out);
}